// Round 13
// baseline (256.843 us; speedup 1.0000x reference)
//
#include <hip/hip_runtime.h>
#include <math.h>

#define D 128
#define H 128
#define BQ 1024
#define M 512
#define NNODES 500000
#define K_MAX 8
#define SHORT 16
#define NBLK 2048                  // homogeneous dual-role blocks
#define COPY_N4 ((long)NNODES * D / 4)
#define CS ((long)NBLK * 256)      // copy grid-stride

typedef __attribute__((ext_vector_type(8))) short bf16x8;
typedef __attribute__((ext_vector_type(4))) float f32x4;
typedef __attribute__((ext_vector_type(4))) unsigned u32x4;

// RNE fp32->bf16, packed pair
static __device__ __forceinline__ unsigned pack2bf(float a, float b) {
    unsigned ua = __float_as_uint(a);
    unsigned ub = __float_as_uint(b);
    ua = ua + 0x7fffu + ((ua >> 16) & 1u);
    ub = ub + 0x7fffu + ((ub >> 16) & 1u);
    return (ua >> 16) | (ub & 0xffff0000u);
}

// ---------------------------------------------------------------------------
// Phase 0: W1 bottom half -> bf16, h-major, linear image of swizzled LDS tile.
// Swizzle: k-byte inner ^ ((h&15)<<4)  (verified round 7: 0 bank conflicts)
// ---------------------------------------------------------------------------
__global__ void wconv_kernel(const float* __restrict__ W1,
                             unsigned short* __restrict__ wTswz) {
    const int idx = blockIdx.x * 256 + threadIdx.x;  // 0..16383
    const int h = idx >> 7;
    const int inner = (idx & 127) * 2;               // byte offset within row
    const int k = (inner ^ ((h & 15) << 4)) >> 1;
    const float v = W1[(long)(D + k) * H + h];
    wTswz[idx] = (unsigned short)pack2bf(v, 0.f);
}

// ---------------------------------------------------------------------------
// Phase 1: qh[b][h] = b1[h] + embed[query[b]] . W1top   (fp32)
// ---------------------------------------------------------------------------
__global__ void qproj_kernel(const float* __restrict__ embed,
                             const float* __restrict__ W1,
                             const float* __restrict__ b1,
                             const int* __restrict__ query_idx,
                             float* __restrict__ qh) {
    __shared__ float qrow[D];
    const int b = blockIdx.x;
    const int t = threadIdx.x;
    const long qi = query_idx[b];
    qrow[t] = embed[qi * D + t];
    __syncthreads();
    float acc = b1[t];
#pragma unroll 8
    for (int d = 0; d < D; ++d)
        acc = fmaf(qrow[d], W1[d * H + t], acc);
    qh[b * H + t] = acc;
}

// ---------------------------------------------------------------------------
// Phase 2 (FUSED, HOMOGENEOUS DUAL-ROLE): 2048 identical blocks. Each block
// owns ONE score unit (b, m-half: 4 m-tiles) AND 1/2048 of the node_feat
// copy. The copy's nt load/store pairs (2 groups of 4 f32x4 per tile) are
// interleaved inside the tile loop so HBM copy latency hides under score
// compute, and score's L3 gathers overlap copy HBM traffic. No partition,
// no dispatch-order dependence.
// ---------------------------------------------------------------------------
__global__ __launch_bounds__(256, 4)
void fused_kernel(const float* __restrict__ embed,
                  const unsigned short* __restrict__ wTswz,
                  const float* __restrict__ W2,
                  const float* __restrict__ b2,
                  const int* __restrict__ cand_idx,
                  const float* __restrict__ qh,
                  float* __restrict__ scores,
                  const f32x4* __restrict__ nf_src,
                  f32x4* __restrict__ nf_dst) {
    __shared__ __align__(16) char Bs[32768];   // [h][k] bf16, swizzled
    const int bid = blockIdx.x;
    const int t   = threadIdx.x;

    const int b    = bid >> 1;           // 0..BQ-1
    const int half = bid & 1;            // m-offset half*256
    const long cbase = (long)bid * 256 + t;   // copy base, stride CS, 32 iters

    {   // stage B once: linear copy of pre-swizzled bf16 W1bot (32 KB)
#pragma unroll
        for (int i = 0; i < 8; ++i) {
            const int c = i * 256 + t;
            const uint4 v = ((const uint4*)wTswz)[c];
            *(uint4*)(Bs + (size_t)c * 16) = v;
        }
    }

    const int lane = t & 63;
    const int w    = t >> 6;       // wave id = edge band within tile
    const int g    = lane >> 4;    // k-group
    const int c    = lane & 15;    // row (edge) / col (h) within band
    const int sw   = c << 4;       // full-nibble swizzle (matches wconv)

    // hoist per-row operands: qh and W2 at h = cb*16+c
    float qv[8], w2[8];
#pragma unroll
    for (int cb = 0; cb < 8; ++cb) {
        qv[cb] = qh[b * H + cb * 16 + c];
        w2[cb] = W2[cb * 16 + c];
    }
    const float b2v = b2[0];

    // per-lane candidate indices for the 4 tiles (4 g-lanes share a value)
    int idx[4];
    const int ibase = b * M + half * 256 + w * 16 + c;
#pragma unroll
    for (int mt = 0; mt < 4; ++mt) idx[mt] = cand_idx[ibase + mt * 64];

    __syncthreads();   // Bs ready

    // 1-deep pipeline: prefetch tile 0 gathers
    f32x4 buf[8];
    {
        const float* rp = embed + (long)idx[0] * D + g * 8;
#pragma unroll
        for (int ks = 0; ks < 4; ++ks) {
            buf[2 * ks]     = *(const f32x4*)(rp + ks * 32);
            buf[2 * ks + 1] = *(const f32x4*)(rp + ks * 32 + 4);
        }
    }

#pragma unroll
    for (int mt = 0; mt < 4; ++mt) {
        // ---- copy group A: issue 4 nt loads (k = mt*8 .. +3) ----
        f32x4 ca[4];
#pragma unroll
        for (int j = 0; j < 4; ++j) {
            const long i = cbase + (long)(mt * 8 + j) * CS;
            if (i < COPY_N4) ca[j] = __builtin_nontemporal_load(&nf_src[i]);
        }

        // pack current gathers -> A fragments
        bf16x8 afr[4];
#pragma unroll
        for (int ks = 0; ks < 4; ++ks) {
            u32x4 u;
            u.x = pack2bf(buf[2 * ks].x, buf[2 * ks].y);
            u.y = pack2bf(buf[2 * ks].z, buf[2 * ks].w);
            u.z = pack2bf(buf[2 * ks + 1].x, buf[2 * ks + 1].y);
            u.w = pack2bf(buf[2 * ks + 1].z, buf[2 * ks + 1].w);
            afr[ks] = __builtin_bit_cast(bf16x8, u);
        }
        // prefetch next tile gathers under this tile's compute
        if (mt < 3) {
            const float* rp = embed + (long)idx[mt + 1] * D + g * 8;
#pragma unroll
            for (int ks = 0; ks < 4; ++ks) {
                buf[2 * ks]     = *(const f32x4*)(rp + ks * 32);
                buf[2 * ks + 1] = *(const f32x4*)(rp + ks * 32 + 4);
            }
        }

        // ---- copy group A: stores (waits only on the 4 oldest loads) ----
#pragma unroll
        for (int j = 0; j < 4; ++j) {
            const long i = cbase + (long)(mt * 8 + j) * CS;
            if (i < COPY_N4) __builtin_nontemporal_store(ca[j], &nf_dst[i]);
        }
        // ---- copy group B: issue 4 nt loads (k = mt*8+4 .. +7) ----
        f32x4 cbv[4];
#pragma unroll
        for (int j = 0; j < 4; ++j) {
            const long i = cbase + (long)(mt * 8 + 4 + j) * CS;
            if (i < COPY_N4) cbv[j] = __builtin_nontemporal_load(&nf_src[i]);
        }

        f32x4 acc[8];
#pragma unroll
        for (int cb = 0; cb < 8; ++cb) acc[cb] = (f32x4){0.f, 0.f, 0.f, 0.f};
#pragma unroll
        for (int ks = 0; ks < 4; ++ks) {
            const int koff = (ks * 64 + g * 16) ^ sw;
#pragma unroll
            for (int cb = 0; cb < 8; ++cb) {
                const bf16x8 bv = *(const bf16x8*)(Bs + ((cb * 16 + c) << 8) + koff);
                acc[cb] = __builtin_amdgcn_mfma_f32_16x16x32_bf16(afr[ks], bv, acc[cb], 0, 0, 0);
            }
        }

        // epilogue: relu(qh + acc) . W2 ; butterfly-reduce over 16 c-lanes
        float s0 = 0.f, s1 = 0.f, s2 = 0.f, s3 = 0.f;
#pragma unroll
        for (int cb = 0; cb < 8; ++cb) {
            s0 = fmaf(fmaxf(qv[cb] + acc[cb][0], 0.f), w2[cb], s0);
            s1 = fmaf(fmaxf(qv[cb] + acc[cb][1], 0.f), w2[cb], s1);
            s2 = fmaf(fmaxf(qv[cb] + acc[cb][2], 0.f), w2[cb], s2);
            s3 = fmaf(fmaxf(qv[cb] + acc[cb][3], 0.f), w2[cb], s3);
        }
#pragma unroll
        for (int off = 1; off <= 8; off <<= 1) {
            s0 += __shfl_xor(s0, off);
            s1 += __shfl_xor(s1, off);
            s2 += __shfl_xor(s2, off);
            s3 += __shfl_xor(s3, off);
        }

        // ---- copy group B: stores (MFMA+epilogue covered the latency) ----
#pragma unroll
        for (int j = 0; j < 4; ++j) {
            const long i = cbase + (long)(mt * 8 + 4 + j) * CS;
            if (i < COPY_N4) __builtin_nontemporal_store(cbv[j], &nf_dst[i]);
        }

        if (c == 0) {
            float* out = scores + b * M + half * 256 + mt * 64 + w * 16 + g * 4;
            out[0] = s0 + b2v;
            out[1] = s1 + b2v;
            out[2] = s2 + b2v;
            out[3] = s3 + b2v;
        }
    }
}

// ---------------------------------------------------------------------------
// Phase 3a: approximate top-16 shortlist positions per row (1 wave/row)
// ---------------------------------------------------------------------------
__global__ void topk16_kernel(const float* __restrict__ scores,
                              int* __restrict__ shortpos) {
    const int b = blockIdx.x;
    const int lane = threadIdx.x;
    const float* row = scores + b * M;
    float v[8];
    {
        const float4 x0 = ((const float4*)row)[lane * 2];
        const float4 x1 = ((const float4*)row)[lane * 2 + 1];
        v[0] = x0.x; v[1] = x0.y; v[2] = x0.z; v[3] = x0.w;
        v[4] = x1.x; v[5] = x1.y; v[6] = x1.z; v[7] = x1.w;
    }
    for (int kk = 0; kk < SHORT; ++kk) {
        float bv = v[0];
        int bi = lane * 8;
#pragma unroll
        for (int j = 1; j < 8; ++j)
            if (v[j] > bv) { bv = v[j]; bi = lane * 8 + j; }
#pragma unroll
        for (int off = 32; off >= 1; off >>= 1) {
            const float ov = __shfl_xor(bv, off);
            const int   oi = __shfl_xor(bi, off);
            if (ov > bv || (ov == bv && oi < bi)) { bv = ov; bi = oi; }
        }
        if (lane == 0) shortpos[b * SHORT + kk] = bi;
        if ((bi >> 3) == lane) v[bi & 7] = -3.402823466e38f;
    }
}

// ---------------------------------------------------------------------------
// Phase 3b: exact fp32 rescore of shortlist, top-k with lax.top_k semantics
// ---------------------------------------------------------------------------
__global__ __launch_bounds__(128)
void refine_kernel(const float* __restrict__ embed,
                   const float* __restrict__ W1,
                   const float* __restrict__ W2,
                   const float* __restrict__ qh,
                   const int* __restrict__ cand_idx,
                   const int* __restrict__ shortpos,
                   const int* __restrict__ topk_ptr,
                   int* __restrict__ top_nodes) {
    __shared__ float crows[SHORT][D];
    __shared__ float red[SHORT][D];
    __shared__ int spos[SHORT];
    const int b = blockIdx.x;
    const int t = threadIdx.x;

    if (t < SHORT) spos[t] = shortpos[b * SHORT + t];
    __syncthreads();
    {
        const int cc = t >> 3;
        const int d0 = (t & 7) * 16;
        const long node = cand_idx[b * M + spos[cc]];
        const float4* rp = (const float4*)(embed + node * D);
        float4* wp = (float4*)&crows[cc][d0];
#pragma unroll
        for (int j = 0; j < 4; ++j) wp[j] = rp[d0 / 4 + j];
    }
    __syncthreads();

    float acc[SHORT];
#pragma unroll
    for (int cc = 0; cc < SHORT; ++cc) acc[cc] = 0.f;
    const float* W1bot = W1 + (long)D * H;
    for (int d = 0; d < D; ++d) {
        const float w1v = W1bot[d * H + t];
#pragma unroll
        for (int cc = 0; cc < SHORT; ++cc)
            acc[cc] = fmaf(crows[cc][d], w1v, acc[cc]);
    }
    const float qv = qh[b * H + t];
    const float w2 = W2[t];
#pragma unroll
    for (int cc = 0; cc < SHORT; ++cc)
        red[cc][t] = fmaxf(qv + acc[cc], 0.f) * w2;
    __syncthreads();

    if (t < 64) {
#pragma unroll
        for (int cc = 0; cc < SHORT; ++cc) {
            float v = red[cc][t] + red[cc][t + 64];
#pragma unroll
            for (int off = 32; off >= 1; off >>= 1) v += __shfl_xor(v, off);
            if (t == 0) red[cc][0] = v;
        }
    }
    __syncthreads();

    if (t == 0) {
        int k = *topk_ptr;
        if (k > K_MAX) k = K_MAX;
        unsigned used = 0;
        for (int kk = 0; kk < K_MAX; ++kk) {
            if (kk < k) {
                int best = -1, bpos = 0x7fffffff;
                float bv = 0.f;
                for (int cc = 0; cc < SHORT; ++cc) {
                    if (used & (1u << cc)) continue;
                    const float v = red[cc][0];
                    const int p = spos[cc];
                    if (best < 0 || v > bv || (v == bv && p < bpos)) {
                        best = cc; bv = v; bpos = p;
                    }
                }
                used |= 1u << best;
                top_nodes[b * K_MAX + kk] = cand_idx[b * M + bpos];
            } else {
                top_nodes[b * K_MAX + kk] = -1;
            }
        }
    }
}

// ---------------------------------------------------------------------------
// Phase 4: zero the selected rows (after fused copy + refine)
// ---------------------------------------------------------------------------
__global__ void zero_rows_kernel(const int* __restrict__ top_nodes,
                                 float* __restrict__ masked) {
    const int node = top_nodes[blockIdx.x];
    if (node < 0) return;
    masked[(long)node * D + threadIdx.x] = 0.f;
}

// ---------------------------------------------------------------------------
extern "C" void kernel_launch(void* const* d_in, const int* in_sizes, int n_in,
                              void* d_out, int out_size, void* d_ws, size_t ws_size,
                              hipStream_t stream) {
    const float* embed     = (const float*)d_in[0];
    const float* node_feat = (const float*)d_in[1];
    const float* W1        = (const float*)d_in[2];
    const float* b1        = (const float*)d_in[3];
    const float* W2        = (const float*)d_in[4];
    const float* b2        = (const float*)d_in[5];
    const int*   query_idx = (const int*)d_in[6];
    const int*   cand_idx  = (const int*)d_in[7];
    const int*   topk_ptr  = (const int*)d_in[8];

    float* scores = (float*)d_out;                 // B*M
    float* masked = (float*)d_out + (long)BQ * M;  // N*D

    // ws layout
    char* p = (char*)d_ws;
    float*          qh        = (float*)p;          p += (long)BQ * H * 4;
    int*            shortpos  = (int*)p;            p += (long)BQ * SHORT * 4;
    int*            top_nodes = (int*)p;            p += (long)BQ * K_MAX * 4;
    unsigned short* wTswz     = (unsigned short*)p;

    wconv_kernel<<<(H * D) / 256, 256, 0, stream>>>(W1, wTswz);
    qproj_kernel<<<BQ, H, 0, stream>>>(embed, W1, b1, query_idx, qh);

    fused_kernel<<<NBLK, 256, 0, stream>>>(
        embed, wTswz, W2, b2, cand_idx, qh, scores,
        (const f32x4*)node_feat, (f32x4*)masked);

    topk16_kernel<<<BQ, 64, 0, stream>>>(scores, shortpos);
    refine_kernel<<<BQ, 128, 0, stream>>>(embed, W1, W2, qh, cand_idx,
                                          shortpos, topk_ptr, top_nodes);
    zero_rows_kernel<<<BQ * K_MAX, D, 0, stream>>>(top_nodes, masked);
}

// Round 14
// 239.106 us; speedup vs baseline: 1.0742x; 1.0742x over previous
//
#include <hip/hip_runtime.h>
#include <math.h>

#define D 128
#define H 128
#define BQ 1024
#define M 512
#define NNODES 500000
#define K_MAX 8
#define SHORT 16
#define NCOPYP 1024                // 512-thread copy blocks, FIRST in grid
#define NSCORE 1024                // 512-thread score blocks (one per row b)
#define COPY_N4 ((long)NNODES * D / 4)
#define CS ((long)NCOPYP * 512)    // copy grid-stride

typedef __attribute__((ext_vector_type(8))) short bf16x8;
typedef __attribute__((ext_vector_type(4))) float f32x4;
typedef __attribute__((ext_vector_type(4))) unsigned u32x4;

// RNE fp32->bf16, packed pair
static __device__ __forceinline__ unsigned pack2bf(float a, float b) {
    unsigned ua = __float_as_uint(a);
    unsigned ub = __float_as_uint(b);
    ua = ua + 0x7fffu + ((ua >> 16) & 1u);
    ub = ub + 0x7fffu + ((ub >> 16) & 1u);
    return (ua >> 16) | (ub & 0xffff0000u);
}

// ---------------------------------------------------------------------------
// Phase 1 (merged pre-kernel): qproj for all b; blocks 0..127 also convert
// W1-bottom -> bf16 swizzled image (k-byte inner ^ ((h&15)<<4); 0-conflict).
// ---------------------------------------------------------------------------
__global__ __launch_bounds__(128)
void pre_kernel(const float* __restrict__ embed,
                const float* __restrict__ W1,
                const float* __restrict__ b1,
                const int* __restrict__ query_idx,
                float* __restrict__ qh,
                unsigned short* __restrict__ wTswz) {
    __shared__ float qrow[D];
    const int b = blockIdx.x;
    const int t = threadIdx.x;

    if (b < 128) {   // wconv side-job: 128 elements per block
        const int idx = b * 128 + t;
        const int h = idx >> 7;
        const int inner = (idx & 127) * 2;
        const int k = (inner ^ ((h & 15) << 4)) >> 1;
        wTswz[idx] = (unsigned short)pack2bf(W1[(long)(D + k) * H + h], 0.f);
    }

    const long qi = query_idx[b];
    qrow[t] = embed[qi * D + t];
    __syncthreads();
    float acc = b1[t];
#pragma unroll 8
    for (int d = 0; d < D; ++d)
        acc = fmaf(qrow[d], W1[d * H + t], acc);
    qh[b * H + t] = acc;
}

// ---------------------------------------------------------------------------
// Phase 2 (FUSED, 512-thread blocks): copy-first partition at FULL occupancy.
//   bid <  NCOPYP : copy block — 8 waves of nt streaming. 4 blocks/CU
//                   (thread-slot cap) x 8 waves = 32 waves/CU -> standalone
//                   copy speed (~6.3 TB/s), unlike the 20-wave 256T config.
//   bid >= NCOPYP : score block — row b, 8 waves = 2 m-halves x 4 bands;
//                   per-wave body identical to the proven 56-VGPR round-12
//                   body (1-deep gather pipeline, swizzled LDS B).
// launch_bounds(512,8): VGPR cap 64 (body measured 56). LDS 4x32KB=128<=160.
// ---------------------------------------------------------------------------
__global__ __launch_bounds__(512, 8)
void fused_kernel(const float* __restrict__ embed,
                  const unsigned short* __restrict__ wTswz,
                  const float* __restrict__ W2,
                  const float* __restrict__ b2,
                  const int* __restrict__ cand_idx,
                  const float* __restrict__ qh,
                  float* __restrict__ scores,
                  const f32x4* __restrict__ nf_src,
                  f32x4* __restrict__ nf_dst) {
    __shared__ __align__(16) char Bs[32768];   // [h][k] bf16, swizzled
    const int bid = blockIdx.x;
    const int t   = threadIdx.x;               // 0..511

    if (bid < NCOPYP) {
        // ---------------- copy block: nontemporal streaming, 4x unroll -----
        long i = (long)bid * 512 + t;
        for (; i + 3 * CS < COPY_N4; i += 4 * CS) {
            const f32x4 v0 = __builtin_nontemporal_load(&nf_src[i]);
            const f32x4 v1 = __builtin_nontemporal_load(&nf_src[i + CS]);
            const f32x4 v2 = __builtin_nontemporal_load(&nf_src[i + 2 * CS]);
            const f32x4 v3 = __builtin_nontemporal_load(&nf_src[i + 3 * CS]);
            __builtin_nontemporal_store(v0, &nf_dst[i]);
            __builtin_nontemporal_store(v1, &nf_dst[i + CS]);
            __builtin_nontemporal_store(v2, &nf_dst[i + 2 * CS]);
            __builtin_nontemporal_store(v3, &nf_dst[i + 3 * CS]);
        }
        for (; i < COPY_N4; i += CS) {
            const f32x4 v = __builtin_nontemporal_load(&nf_src[i]);
            __builtin_nontemporal_store(v, &nf_dst[i]);
        }
        return;
    }

    // ------------------- score block: row b, 8 waves ----------------------
    const int b = bid - NCOPYP;          // 0..BQ-1

    {   // stage B once: 2048 uint4 chunks / 512 threads = 4 each
#pragma unroll
        for (int i = 0; i < 4; ++i) {
            const int c = i * 512 + t;
            const uint4 v = ((const uint4*)wTswz)[c];
            *(uint4*)(Bs + (size_t)c * 16) = v;
        }
    }

    const int lane = t & 63;
    const int w    = t >> 6;       // 0..7
    const int band = w & 3;        // edge band within tile
    const int hf   = w >> 2;       // m-half
    const int g    = lane >> 4;    // k-group
    const int c    = lane & 15;    // row (edge) / col (h) within band
    const int sw   = c << 4;       // full-nibble swizzle (matches wconv)

    // hoist per-row operands: qh and W2 at h = cb*16+c
    float qv[8], w2[8];
#pragma unroll
    for (int cb = 0; cb < 8; ++cb) {
        qv[cb] = qh[b * H + cb * 16 + c];
        w2[cb] = W2[cb * 16 + c];
    }
    const float b2v = b2[0];

    // per-lane candidate indices for the 4 tiles (4 g-lanes share a value)
    int idx[4];
    const int ibase = b * M + hf * 256 + band * 16 + c;
#pragma unroll
    for (int mt = 0; mt < 4; ++mt) idx[mt] = cand_idx[ibase + mt * 64];

    __syncthreads();   // Bs ready

    // 1-deep pipeline: prefetch tile 0
    f32x4 buf[8];
    {
        const float* rp = embed + (long)idx[0] * D + g * 8;
#pragma unroll
        for (int ks = 0; ks < 4; ++ks) {
            buf[2 * ks]     = *(const f32x4*)(rp + ks * 32);
            buf[2 * ks + 1] = *(const f32x4*)(rp + ks * 32 + 4);
        }
    }

#pragma unroll
    for (int mt = 0; mt < 4; ++mt) {
        // pack current gathers -> A fragments
        bf16x8 afr[4];
#pragma unroll
        for (int ks = 0; ks < 4; ++ks) {
            u32x4 u;
            u.x = pack2bf(buf[2 * ks].x, buf[2 * ks].y);
            u.y = pack2bf(buf[2 * ks].z, buf[2 * ks].w);
            u.z = pack2bf(buf[2 * ks + 1].x, buf[2 * ks + 1].y);
            u.w = pack2bf(buf[2 * ks + 1].z, buf[2 * ks + 1].w);
            afr[ks] = __builtin_bit_cast(bf16x8, u);
        }
        // prefetch next tile under this tile's MFMA + epilogue
        if (mt < 3) {
            const float* rp = embed + (long)idx[mt + 1] * D + g * 8;
#pragma unroll
            for (int ks = 0; ks < 4; ++ks) {
                buf[2 * ks]     = *(const f32x4*)(rp + ks * 32);
                buf[2 * ks + 1] = *(const f32x4*)(rp + ks * 32 + 4);
            }
        }

        f32x4 acc[8];
#pragma unroll
        for (int cb = 0; cb < 8; ++cb) acc[cb] = (f32x4){0.f, 0.f, 0.f, 0.f};
#pragma unroll
        for (int ks = 0; ks < 4; ++ks) {
            const int koff = (ks * 64 + g * 16) ^ sw;
#pragma unroll
            for (int cb = 0; cb < 8; ++cb) {
                const bf16x8 bv = *(const bf16x8*)(Bs + ((cb * 16 + c) << 8) + koff);
                acc[cb] = __builtin_amdgcn_mfma_f32_16x16x32_bf16(afr[ks], bv, acc[cb], 0, 0, 0);
            }
        }

        // epilogue: relu(qh + acc) . W2 ; butterfly-reduce over 16 c-lanes
        float s0 = 0.f, s1 = 0.f, s2 = 0.f, s3 = 0.f;
#pragma unroll
        for (int cb = 0; cb < 8; ++cb) {
            s0 = fmaf(fmaxf(qv[cb] + acc[cb][0], 0.f), w2[cb], s0);
            s1 = fmaf(fmaxf(qv[cb] + acc[cb][1], 0.f), w2[cb], s1);
            s2 = fmaf(fmaxf(qv[cb] + acc[cb][2], 0.f), w2[cb], s2);
            s3 = fmaf(fmaxf(qv[cb] + acc[cb][3], 0.f), w2[cb], s3);
        }
#pragma unroll
        for (int off = 1; off <= 8; off <<= 1) {
            s0 += __shfl_xor(s0, off);
            s1 += __shfl_xor(s1, off);
            s2 += __shfl_xor(s2, off);
            s3 += __shfl_xor(s3, off);
        }
        if (c == 0) {
            float* out = scores + b * M + hf * 256 + mt * 64 + band * 16 + g * 4;
            out[0] = s0 + b2v;
            out[1] = s1 + b2v;
            out[2] = s2 + b2v;
            out[3] = s3 + b2v;
        }
    }
}

// ---------------------------------------------------------------------------
// Phase 3 (merged): top-16 shortlist -> exact fp32 rescore -> top-k select
// (lax.top_k semantics) -> zero selected rows. One block (128T) per row b.
// Runs after fused_kernel, so the copy into masked is already complete.
// ---------------------------------------------------------------------------
__global__ __launch_bounds__(128)
void topkrefine_kernel(const float* __restrict__ embed,
                       const float* __restrict__ W1,
                       const float* __restrict__ W2,
                       const float* __restrict__ qh,
                       const int* __restrict__ cand_idx,
                       const float* __restrict__ scores,
                       const int* __restrict__ topk_ptr,
                       float* __restrict__ masked) {
    __shared__ float crows[SHORT][D];
    __shared__ float red[SHORT][D];
    __shared__ int spos[SHORT];
    __shared__ int tnodes[K_MAX];
    __shared__ int kshare;
    const int b = blockIdx.x;
    const int t = threadIdx.x;

    // ---- phase A: approximate top-16 positions (wave 0 only) ----
    if (t < 64) {
        const float* row = scores + b * M;
        float v[8];
        const float4 x0 = ((const float4*)row)[t * 2];
        const float4 x1 = ((const float4*)row)[t * 2 + 1];
        v[0] = x0.x; v[1] = x0.y; v[2] = x0.z; v[3] = x0.w;
        v[4] = x1.x; v[5] = x1.y; v[6] = x1.z; v[7] = x1.w;
        for (int kk = 0; kk < SHORT; ++kk) {
            float bv = v[0];
            int bi = t * 8;
#pragma unroll
            for (int j = 1; j < 8; ++j)
                if (v[j] > bv) { bv = v[j]; bi = t * 8 + j; }
#pragma unroll
            for (int off = 32; off >= 1; off >>= 1) {
                const float ov = __shfl_xor(bv, off);
                const int   oi = __shfl_xor(bi, off);
                if (ov > bv || (ov == bv && oi < bi)) { bv = ov; bi = oi; }
            }
            if (t == 0) spos[kk] = bi;
            if ((bi >> 3) == t) v[bi & 7] = -3.402823466e38f;
        }
    }
    __syncthreads();

    // ---- phase B: exact fp32 rescore of the 16 shortlisted candidates ----
    {
        const int cc = t >> 3;
        const int d0 = (t & 7) * 16;
        const long node = cand_idx[b * M + spos[cc]];
        const float4* rp = (const float4*)(embed + node * D);
        float4* wp = (float4*)&crows[cc][d0];
#pragma unroll
        for (int j = 0; j < 4; ++j) wp[j] = rp[d0 / 4 + j];
    }
    __syncthreads();

    float acc[SHORT];
#pragma unroll
    for (int cc = 0; cc < SHORT; ++cc) acc[cc] = 0.f;
    const float* W1bot = W1 + (long)D * H;
    for (int d = 0; d < D; ++d) {
        const float w1v = W1bot[d * H + t];
#pragma unroll
        for (int cc = 0; cc < SHORT; ++cc)
            acc[cc] = fmaf(crows[cc][d], w1v, acc[cc]);
    }
    const float qv = qh[b * H + t];
    const float w2 = W2[t];
#pragma unroll
    for (int cc = 0; cc < SHORT; ++cc)
        red[cc][t] = fmaxf(qv + acc[cc], 0.f) * w2;
    __syncthreads();

    if (t < 64) {
#pragma unroll
        for (int cc = 0; cc < SHORT; ++cc) {
            float v = red[cc][t] + red[cc][t + 64];
#pragma unroll
            for (int off = 32; off >= 1; off >>= 1) v += __shfl_xor(v, off);
            if (t == 0) red[cc][0] = v;
        }
    }
    __syncthreads();

    // ---- phase C: select top-k (value desc, position asc) ----
    if (t == 0) {
        int k = *topk_ptr;
        if (k > K_MAX) k = K_MAX;
        kshare = k;
        unsigned used = 0;
        for (int kk = 0; kk < k; ++kk) {
            int best = -1, bpos = 0x7fffffff;
            float bv = 0.f;
            for (int cc = 0; cc < SHORT; ++cc) {
                if (used & (1u << cc)) continue;
                const float v = red[cc][0];
                const int p = spos[cc];
                if (best < 0 || v > bv || (v == bv && p < bpos)) {
                    best = cc; bv = v; bpos = p;
                }
            }
            used |= 1u << best;
            tnodes[kk] = cand_idx[b * M + bpos];
        }
    }
    __syncthreads();

    // ---- phase D: zero the selected rows (copy already completed) ----
    for (int kk = 0; kk < kshare; ++kk)
        masked[(long)tnodes[kk] * D + t] = 0.f;
}

// ---------------------------------------------------------------------------
extern "C" void kernel_launch(void* const* d_in, const int* in_sizes, int n_in,
                              void* d_out, int out_size, void* d_ws, size_t ws_size,
                              hipStream_t stream) {
    const float* embed     = (const float*)d_in[0];
    const float* node_feat = (const float*)d_in[1];
    const float* W1        = (const float*)d_in[2];
    const float* b1        = (const float*)d_in[3];
    const float* W2        = (const float*)d_in[4];
    const float* b2        = (const float*)d_in[5];
    const int*   query_idx = (const int*)d_in[6];
    const int*   cand_idx  = (const int*)d_in[7];
    const int*   topk_ptr  = (const int*)d_in[8];

    float* scores = (float*)d_out;                 // B*M
    float* masked = (float*)d_out + (long)BQ * M;  // N*D

    // ws layout
    char* p = (char*)d_ws;
    float*          qh    = (float*)p;              p += (long)BQ * H * 4;
    unsigned short* wTswz = (unsigned short*)p;

    pre_kernel<<<BQ, 128, 0, stream>>>(embed, W1, b1, query_idx, qh, wTswz);

    fused_kernel<<<NCOPYP + NSCORE, 512, 0, stream>>>(
        embed, wTswz, W2, b2, cand_idx, qh, scores,
        (const f32x4*)node_feat, (f32x4*)masked);

    topkrefine_kernel<<<BQ, 128, 0, stream>>>(embed, W1, W2, qh, cand_idx,
                                              scores, topk_ptr, masked);
}

// Round 15
// 173.960 us; speedup vs baseline: 1.4764x; 1.3745x over previous
//
#include <hip/hip_runtime.h>
#include <math.h>

#define D 128
#define H 128
#define BQ 1024
#define M 512
#define NNODES 500000
#define K_MAX 8
#define SHORT 16
#define NCOPYP 1024                 // pure copy blocks, FIRST in grid
#define NSCORE 2048                 // score blocks (b, m-half), each + copy suffix
#define COPY_N4 ((long)NNODES * D / 4)       // 16,000,000 f32x4
#define S1 8192                     // f32x4 per pure-copy block  (32 iters x 256)
#define S2 4096                     // f32x4 per score-block suffix (16 iters x 256)

typedef __attribute__((ext_vector_type(8))) short bf16x8;
typedef __attribute__((ext_vector_type(4))) float f32x4;
typedef __attribute__((ext_vector_type(4))) unsigned u32x4;

// RNE fp32->bf16, packed pair
static __device__ __forceinline__ unsigned pack2bf(float a, float b) {
    unsigned ua = __float_as_uint(a);
    unsigned ub = __float_as_uint(b);
    ua = ua + 0x7fffu + ((ua >> 16) & 1u);
    ub = ub + 0x7fffu + ((ub >> 16) & 1u);
    return (ua >> 16) | (ub & 0xffff0000u);
}

// ---------------------------------------------------------------------------
// Pre-kernel (merged): qproj for all b; blocks 0..127 also build the bf16
// swizzled W1-bottom image (k-byte inner ^ ((h&15)<<4); 0-conflict, r7).
// ---------------------------------------------------------------------------
__global__ __launch_bounds__(128)
void pre_kernel(const float* __restrict__ embed,
                const float* __restrict__ W1,
                const float* __restrict__ b1,
                const int* __restrict__ query_idx,
                float* __restrict__ qh,
                unsigned short* __restrict__ wTswz) {
    __shared__ float qrow[D];
    const int b = blockIdx.x;
    const int t = threadIdx.x;

    if (b < 128) {   // wconv side-job: 128 elements per block
        const int idx = b * 128 + t;
        const int h = idx >> 7;
        const int inner = (idx & 127) * 2;
        const int k = (inner ^ ((h & 15) << 4)) >> 1;
        wTswz[idx] = (unsigned short)pack2bf(W1[(long)(D + k) * H + h], 0.f);
    }

    const long qi = query_idx[b];
    qrow[t] = embed[qi * D + t];
    __syncthreads();
    float acc = b1[t];
#pragma unroll 8
    for (int d = 0; d < D; ++d)
        acc = fmaf(qrow[d], W1[d * H + t], acc);
    qh[b * H + t] = acc;
}

// ---------------------------------------------------------------------------
// Fused kernel: balanced copy ownership.
//   bid <  NCOPYP : pure copy block, slice S1 (dispatched first; from t=0 the
//                   resident mix is ~4 copy + ~1 score per CU -> HBM and L3
//                   both busy immediately).
//   bid >= NCOPYP : score unit (b, m-half, 4 m-tiles; proven 56-VGPR r12
//                   body), then a SEQUENTIAL copy suffix of S2 (registers
//                   dead after score -> reuse, no spill; staggered block
//                   completion overlaps suffix copy with remaining gathers).
// launch_bounds(256,4): VGPR cap 128 (collapse-free regime; r10/r14's 8w/EU
// configs clamp to 32 VGPR and spill).
// ---------------------------------------------------------------------------
__global__ __launch_bounds__(256, 4)
void fused_kernel(const float* __restrict__ embed,
                  const unsigned short* __restrict__ wTswz,
                  const float* __restrict__ W2,
                  const float* __restrict__ b2,
                  const int* __restrict__ cand_idx,
                  const float* __restrict__ qh,
                  float* __restrict__ scores,
                  const f32x4* __restrict__ nf_src,
                  f32x4* __restrict__ nf_dst) {
    __shared__ __align__(16) char Bs[32768];   // [h][k] bf16, swizzled
    const int bid = blockIdx.x;
    const int t   = threadIdx.x;

    if (bid < NCOPYP) {
        // ---- pure copy block: contiguous S1 slice, nt, 4x unroll ----------
        const long base = (long)bid * S1 + t;
#pragma unroll 4
        for (int k = 0; k < S1 / 256; ++k) {
            const long i = base + (long)k * 256;
            if (i < COPY_N4) {
                const f32x4 v = __builtin_nontemporal_load(&nf_src[i]);
                __builtin_nontemporal_store(v, &nf_dst[i]);
            }
        }
        return;
    }

    // ------------------- score unit: (b, half), 4 m-tiles ------------------
    const int sid  = bid - NCOPYP;       // 0..NSCORE-1
    const int b    = sid >> 1;           // 0..BQ-1
    const int half = sid & 1;            // m-offset half*256

    {   // stage B once: linear copy of pre-swizzled bf16 W1bot (32 KB)
#pragma unroll
        for (int i = 0; i < 8; ++i) {
            const int c = i * 256 + t;
            const uint4 v = ((const uint4*)wTswz)[c];
            *(uint4*)(Bs + (size_t)c * 16) = v;
        }
    }

    const int lane = t & 63;
    const int w    = t >> 6;       // wave id = edge band within tile
    const int g    = lane >> 4;    // k-group
    const int c    = lane & 15;    // row (edge) / col (h) within band
    const int sw   = c << 4;       // full-nibble swizzle (matches wconv)

    // hoist per-row operands: qh and W2 at h = cb*16+c
    float qv[8], w2[8];
#pragma unroll
    for (int cb = 0; cb < 8; ++cb) {
        qv[cb] = qh[b * H + cb * 16 + c];
        w2[cb] = W2[cb * 16 + c];
    }
    const float b2v = b2[0];

    // per-lane candidate indices for the 4 tiles (4 g-lanes share a value)
    int idx[4];
    const int ibase = b * M + half * 256 + w * 16 + c;
#pragma unroll
    for (int mt = 0; mt < 4; ++mt) idx[mt] = cand_idx[ibase + mt * 64];

    __syncthreads();   // Bs ready

    // 1-deep pipeline: prefetch tile 0
    f32x4 buf[8];
    {
        const float* rp = embed + (long)idx[0] * D + g * 8;
#pragma unroll
        for (int ks = 0; ks < 4; ++ks) {
            buf[2 * ks]     = *(const f32x4*)(rp + ks * 32);
            buf[2 * ks + 1] = *(const f32x4*)(rp + ks * 32 + 4);
        }
    }

#pragma unroll
    for (int mt = 0; mt < 4; ++mt) {
        // pack current gathers -> A fragments
        bf16x8 afr[4];
#pragma unroll
        for (int ks = 0; ks < 4; ++ks) {
            u32x4 u;
            u.x = pack2bf(buf[2 * ks].x, buf[2 * ks].y);
            u.y = pack2bf(buf[2 * ks].z, buf[2 * ks].w);
            u.z = pack2bf(buf[2 * ks + 1].x, buf[2 * ks + 1].y);
            u.w = pack2bf(buf[2 * ks + 1].z, buf[2 * ks + 1].w);
            afr[ks] = __builtin_bit_cast(bf16x8, u);
        }
        // prefetch next tile under this tile's MFMA + epilogue
        if (mt < 3) {
            const float* rp = embed + (long)idx[mt + 1] * D + g * 8;
#pragma unroll
            for (int ks = 0; ks < 4; ++ks) {
                buf[2 * ks]     = *(const f32x4*)(rp + ks * 32);
                buf[2 * ks + 1] = *(const f32x4*)(rp + ks * 32 + 4);
            }
        }

        f32x4 acc[8];
#pragma unroll
        for (int cb = 0; cb < 8; ++cb) acc[cb] = (f32x4){0.f, 0.f, 0.f, 0.f};
#pragma unroll
        for (int ks = 0; ks < 4; ++ks) {
            const int koff = (ks * 64 + g * 16) ^ sw;
#pragma unroll
            for (int cb = 0; cb < 8; ++cb) {
                const bf16x8 bv = *(const bf16x8*)(Bs + ((cb * 16 + c) << 8) + koff);
                acc[cb] = __builtin_amdgcn_mfma_f32_16x16x32_bf16(afr[ks], bv, acc[cb], 0, 0, 0);
            }
        }

        // epilogue: relu(qh + acc) . W2 ; butterfly-reduce over 16 c-lanes
        float s0 = 0.f, s1 = 0.f, s2 = 0.f, s3 = 0.f;
#pragma unroll
        for (int cb = 0; cb < 8; ++cb) {
            s0 = fmaf(fmaxf(qv[cb] + acc[cb][0], 0.f), w2[cb], s0);
            s1 = fmaf(fmaxf(qv[cb] + acc[cb][1], 0.f), w2[cb], s1);
            s2 = fmaf(fmaxf(qv[cb] + acc[cb][2], 0.f), w2[cb], s2);
            s3 = fmaf(fmaxf(qv[cb] + acc[cb][3], 0.f), w2[cb], s3);
        }
#pragma unroll
        for (int off = 1; off <= 8; off <<= 1) {
            s0 += __shfl_xor(s0, off);
            s1 += __shfl_xor(s1, off);
            s2 += __shfl_xor(s2, off);
            s3 += __shfl_xor(s3, off);
        }
        if (c == 0) {
            float* out = scores + b * M + half * 256 + mt * 64 + w * 16 + g * 4;
            out[0] = s0 + b2v;
            out[1] = s1 + b2v;
            out[2] = s2 + b2v;
            out[3] = s3 + b2v;
        }
    }

    // ---- copy suffix: contiguous S2 slice AFTER score (registers dead) ----
    {
        const long base = (long)NCOPYP * S1 + (long)sid * S2 + t;
#pragma unroll 4
        for (int k = 0; k < S2 / 256; ++k) {
            const long i = base + (long)k * 256;
            if (i < COPY_N4) {
                const f32x4 v = __builtin_nontemporal_load(&nf_src[i]);
                __builtin_nontemporal_store(v, &nf_dst[i]);
            }
        }
    }
}

// ---------------------------------------------------------------------------
// Post-kernel (merged): top-16 shortlist -> exact fp32 rescore -> top-k
// select (lax.top_k semantics) -> zero selected rows. 1 block (128T)/row b.
// ---------------------------------------------------------------------------
__global__ __launch_bounds__(128)
void topkrefine_kernel(const float* __restrict__ embed,
                       const float* __restrict__ W1,
                       const float* __restrict__ W2,
                       const float* __restrict__ qh,
                       const int* __restrict__ cand_idx,
                       const float* __restrict__ scores,
                       const int* __restrict__ topk_ptr,
                       float* __restrict__ masked) {
    __shared__ float crows[SHORT][D];
    __shared__ float red[SHORT][D];
    __shared__ int spos[SHORT];
    __shared__ int tnodes[K_MAX];
    __shared__ int kshare;
    const int b = blockIdx.x;
    const int t = threadIdx.x;

    // ---- phase A: approximate top-16 positions (wave 0 only) ----
    if (t < 64) {
        const float* row = scores + b * M;
        float v[8];
        const float4 x0 = ((const float4*)row)[t * 2];
        const float4 x1 = ((const float4*)row)[t * 2 + 1];
        v[0] = x0.x; v[1] = x0.y; v[2] = x0.z; v[3] = x0.w;
        v[4] = x1.x; v[5] = x1.y; v[6] = x1.z; v[7] = x1.w;
        for (int kk = 0; kk < SHORT; ++kk) {
            float bv = v[0];
            int bi = t * 8;
#pragma unroll
            for (int j = 1; j < 8; ++j)
                if (v[j] > bv) { bv = v[j]; bi = t * 8 + j; }
#pragma unroll
            for (int off = 32; off >= 1; off >>= 1) {
                const float ov = __shfl_xor(bv, off);
                const int   oi = __shfl_xor(bi, off);
                if (ov > bv || (ov == bv && oi < bi)) { bv = ov; bi = oi; }
            }
            if (t == 0) spos[kk] = bi;
            if ((bi >> 3) == t) v[bi & 7] = -3.402823466e38f;
        }
    }
    __syncthreads();

    // ---- phase B: exact fp32 rescore of the 16 shortlisted candidates ----
    {
        const int cc = t >> 3;
        const int d0 = (t & 7) * 16;
        const long node = cand_idx[b * M + spos[cc]];
        const float4* rp = (const float4*)(embed + node * D);
        float4* wp = (float4*)&crows[cc][d0];
#pragma unroll
        for (int j = 0; j < 4; ++j) wp[j] = rp[d0 / 4 + j];
    }
    __syncthreads();

    float acc[SHORT];
#pragma unroll
    for (int cc = 0; cc < SHORT; ++cc) acc[cc] = 0.f;
    const float* W1bot = W1 + (long)D * H;
    for (int d = 0; d < D; ++d) {
        const float w1v = W1bot[d * H + t];
#pragma unroll
        for (int cc = 0; cc < SHORT; ++cc)
            acc[cc] = fmaf(crows[cc][d], w1v, acc[cc]);
    }
    const float qv = qh[b * H + t];
    const float w2 = W2[t];
#pragma unroll
    for (int cc = 0; cc < SHORT; ++cc)
        red[cc][t] = fmaxf(qv + acc[cc], 0.f) * w2;
    __syncthreads();

    if (t < 64) {
#pragma unroll
        for (int cc = 0; cc < SHORT; ++cc) {
            float v = red[cc][t] + red[cc][t + 64];
#pragma unroll
            for (int off = 32; off >= 1; off >>= 1) v += __shfl_xor(v, off);
            if (t == 0) red[cc][0] = v;
        }
    }
    __syncthreads();

    // ---- phase C: select top-k (value desc, position asc) ----
    if (t == 0) {
        int k = *topk_ptr;
        if (k > K_MAX) k = K_MAX;
        kshare = k;
        unsigned used = 0;
        for (int kk = 0; kk < k; ++kk) {
            int best = -1, bpos = 0x7fffffff;
            float bv = 0.f;
            for (int cc = 0; cc < SHORT; ++cc) {
                if (used & (1u << cc)) continue;
                const float v = red[cc][0];
                const int p = spos[cc];
                if (best < 0 || v > bv || (v == bv && p < bpos)) {
                    best = cc; bv = v; bpos = p;
                }
            }
            used |= 1u << best;
            tnodes[kk] = cand_idx[b * M + bpos];
        }
    }
    __syncthreads();

    // ---- phase D: zero the selected rows (copy already completed) ----
    for (int kk = 0; kk < kshare; ++kk)
        masked[(long)tnodes[kk] * D + t] = 0.f;
}

// ---------------------------------------------------------------------------
extern "C" void kernel_launch(void* const* d_in, const int* in_sizes, int n_in,
                              void* d_out, int out_size, void* d_ws, size_t ws_size,
                              hipStream_t stream) {
    const float* embed     = (const float*)d_in[0];
    const float* node_feat = (const float*)d_in[1];
    const float* W1        = (const float*)d_in[2];
    const float* b1        = (const float*)d_in[3];
    const float* W2        = (const float*)d_in[4];
    const float* b2        = (const float*)d_in[5];
    const int*   query_idx = (const int*)d_in[6];
    const int*   cand_idx  = (const int*)d_in[7];
    const int*   topk_ptr  = (const int*)d_in[8];

    float* scores = (float*)d_out;                 // B*M
    float* masked = (float*)d_out + (long)BQ * M;  // N*D

    // ws layout
    char* p = (char*)d_ws;
    float*          qh    = (float*)p;              p += (long)BQ * H * 4;
    unsigned short* wTswz = (unsigned short*)p;

    pre_kernel<<<BQ, 128, 0, stream>>>(embed, W1, b1, query_idx, qh, wTswz);

    fused_kernel<<<NCOPYP + NSCORE, 256, 0, stream>>>(
        embed, wTswz, W2, b2, cand_idx, qh, scores,
        (const f32x4*)node_feat, (f32x4*)masked);

    topkrefine_kernel<<<BQ, 128, 0, stream>>>(embed, W1, W2, qh, cand_idx,
                                              scores, topk_ptr, masked);
}

// Round 16
// 170.997 us; speedup vs baseline: 1.5020x; 1.0173x over previous
//
#include <hip/hip_runtime.h>
#include <math.h>

#define D 128
#define H 128
#define BQ 1024
#define M 512
#define NNODES 500000
#define K_MAX 8
#define SHORT 16
#define NCOPYP 512                  // pure copy blocks (512T), FIRST in grid
#define NSCORE 1024                 // score blocks (512T): one row b each
#define COPY_N4 ((long)NNODES * D / 4)       // 16,000,000 f32x4
#define S1 16384                    // f32x4 per pure-copy block (32 iters x 512)
#define SPLIT ((long)NCOPYP * S1)   // 8,388,608
#define S2ITER 15                   // suffix iters per score block (x512)

typedef __attribute__((ext_vector_type(8))) short bf16x8;
typedef __attribute__((ext_vector_type(4))) float f32x4;
typedef __attribute__((ext_vector_type(4))) unsigned u32x4;

// RNE fp32->bf16, packed pair
static __device__ __forceinline__ unsigned pack2bf(float a, float b) {
    unsigned ua = __float_as_uint(a);
    unsigned ub = __float_as_uint(b);
    ua = ua + 0x7fffu + ((ua >> 16) & 1u);
    ub = ub + 0x7fffu + ((ub >> 16) & 1u);
    return (ua >> 16) | (ub & 0xffff0000u);
}

// ---------------------------------------------------------------------------
// Pre-kernel (merged): qproj for all b; blocks 0..127 also build the bf16
// swizzled W1-bottom image (k-byte inner ^ ((h&15)<<4); 0-conflict, r7).
// ---------------------------------------------------------------------------
__global__ __launch_bounds__(128)
void pre_kernel(const float* __restrict__ embed,
                const float* __restrict__ W1,
                const float* __restrict__ b1,
                const int* __restrict__ query_idx,
                float* __restrict__ qh,
                unsigned short* __restrict__ wTswz) {
    __shared__ float qrow[D];
    const int b = blockIdx.x;
    const int t = threadIdx.x;

    if (b < 128) {   // wconv side-job: 128 elements per block
        const int idx = b * 128 + t;
        const int h = idx >> 7;
        const int inner = (idx & 127) * 2;
        const int k = (inner ^ ((h & 15) << 4)) >> 1;
        wTswz[idx] = (unsigned short)pack2bf(W1[(long)(D + k) * H + h], 0.f);
    }

    const long qi = query_idx[b];
    qrow[t] = embed[qi * D + t];
    __syncthreads();
    float acc = b1[t];
#pragma unroll 8
    for (int d = 0; d < D; ++d)
        acc = fmaf(qrow[d], W1[d * H + t], acc);
    qh[b * H + t] = acc;
}

// ---------------------------------------------------------------------------
// Fused kernel, 512-thread blocks => 4 blocks/CU (thread-slot cap) x 8 waves
// = 32 waves/CU with LDS 4x32KB=128<=160KB. launch_bounds(512,4) keeps the
// VGPR cap at 128 so the allocator picks its natural 56-64 (r10/r14's 8w/EU
// requests clamped to 32 VGPR and spilled — the failure mode to avoid).
//   bid <  NCOPYP : pure copy block, contiguous S1 slice (nt, 4x unroll).
//   bid >= NCOPYP : score row b (8 waves = 2 m-halves x 4 bands; per-wave
//                   body identical to proven r12/r15), then sequential copy
//                   suffix (registers dead after score -> reuse, no spill).
// ---------------------------------------------------------------------------
__global__ __launch_bounds__(512, 4)
void fused_kernel(const float* __restrict__ embed,
                  const unsigned short* __restrict__ wTswz,
                  const float* __restrict__ W2,
                  const float* __restrict__ b2,
                  const int* __restrict__ cand_idx,
                  const float* __restrict__ qh,
                  float* __restrict__ scores,
                  const f32x4* __restrict__ nf_src,
                  f32x4* __restrict__ nf_dst) {
    __shared__ __align__(16) char Bs[32768];   // [h][k] bf16, swizzled
    const int bid = blockIdx.x;
    const int t   = threadIdx.x;               // 0..511

    if (bid < NCOPYP) {
        // ---- pure copy block: contiguous S1 slice, nt, 4x unroll ----------
        const long base = (long)bid * S1 + t;  // always < SPLIT <= COPY_N4
#pragma unroll 4
        for (int k = 0; k < S1 / 512; ++k) {
            const long i = base + (long)k * 512;
            const f32x4 v = __builtin_nontemporal_load(&nf_src[i]);
            __builtin_nontemporal_store(v, &nf_dst[i]);
        }
        return;
    }

    // ------------------- score block: row b, 8 waves -----------------------
    const int b = bid - NCOPYP;          // 0..BQ-1

    {   // stage B once: 2048 uint4 chunks / 512 threads = 4 each
#pragma unroll
        for (int i = 0; i < 4; ++i) {
            const int c = i * 512 + t;
            const uint4 v = ((const uint4*)wTswz)[c];
            *(uint4*)(Bs + (size_t)c * 16) = v;
        }
    }

    const int lane = t & 63;
    const int w    = t >> 6;       // 0..7
    const int band = w & 3;        // edge band within tile
    const int hf   = w >> 2;       // m-half
    const int g    = lane >> 4;    // k-group
    const int c    = lane & 15;    // row (edge) / col (h) within band
    const int sw   = c << 4;       // full-nibble swizzle (matches wconv)

    // hoist per-row operands: qh and W2 at h = cb*16+c
    float qv[8], w2[8];
#pragma unroll
    for (int cb = 0; cb < 8; ++cb) {
        qv[cb] = qh[b * H + cb * 16 + c];
        w2[cb] = W2[cb * 16 + c];
    }
    const float b2v = b2[0];

    // per-lane candidate indices for the 4 tiles (4 g-lanes share a value)
    int idx[4];
    const int ibase = b * M + hf * 256 + band * 16 + c;
#pragma unroll
    for (int mt = 0; mt < 4; ++mt) idx[mt] = cand_idx[ibase + mt * 64];

    __syncthreads();   // Bs ready

    // 1-deep pipeline: prefetch tile 0
    f32x4 buf[8];
    {
        const float* rp = embed + (long)idx[0] * D + g * 8;
#pragma unroll
        for (int ks = 0; ks < 4; ++ks) {
            buf[2 * ks]     = *(const f32x4*)(rp + ks * 32);
            buf[2 * ks + 1] = *(const f32x4*)(rp + ks * 32 + 4);
        }
    }

#pragma unroll
    for (int mt = 0; mt < 4; ++mt) {
        // pack current gathers -> A fragments
        bf16x8 afr[4];
#pragma unroll
        for (int ks = 0; ks < 4; ++ks) {
            u32x4 u;
            u.x = pack2bf(buf[2 * ks].x, buf[2 * ks].y);
            u.y = pack2bf(buf[2 * ks].z, buf[2 * ks].w);
            u.z = pack2bf(buf[2 * ks + 1].x, buf[2 * ks + 1].y);
            u.w = pack2bf(buf[2 * ks + 1].z, buf[2 * ks + 1].w);
            afr[ks] = __builtin_bit_cast(bf16x8, u);
        }
        // prefetch next tile under this tile's MFMA + epilogue
        if (mt < 3) {
            const float* rp = embed + (long)idx[mt + 1] * D + g * 8;
#pragma unroll
            for (int ks = 0; ks < 4; ++ks) {
                buf[2 * ks]     = *(const f32x4*)(rp + ks * 32);
                buf[2 * ks + 1] = *(const f32x4*)(rp + ks * 32 + 4);
            }
        }

        f32x4 acc[8];
#pragma unroll
        for (int cb = 0; cb < 8; ++cb) acc[cb] = (f32x4){0.f, 0.f, 0.f, 0.f};
#pragma unroll
        for (int ks = 0; ks < 4; ++ks) {
            const int koff = (ks * 64 + g * 16) ^ sw;
#pragma unroll
            for (int cb = 0; cb < 8; ++cb) {
                const bf16x8 bv = *(const bf16x8*)(Bs + ((cb * 16 + c) << 8) + koff);
                acc[cb] = __builtin_amdgcn_mfma_f32_16x16x32_bf16(afr[ks], bv, acc[cb], 0, 0, 0);
            }
        }

        // epilogue: relu(qh + acc) . W2 ; butterfly-reduce over 16 c-lanes
        float s0 = 0.f, s1 = 0.f, s2 = 0.f, s3 = 0.f;
#pragma unroll
        for (int cb = 0; cb < 8; ++cb) {
            s0 = fmaf(fmaxf(qv[cb] + acc[cb][0], 0.f), w2[cb], s0);
            s1 = fmaf(fmaxf(qv[cb] + acc[cb][1], 0.f), w2[cb], s1);
            s2 = fmaf(fmaxf(qv[cb] + acc[cb][2], 0.f), w2[cb], s2);
            s3 = fmaf(fmaxf(qv[cb] + acc[cb][3], 0.f), w2[cb], s3);
        }
#pragma unroll
        for (int off = 1; off <= 8; off <<= 1) {
            s0 += __shfl_xor(s0, off);
            s1 += __shfl_xor(s1, off);
            s2 += __shfl_xor(s2, off);
            s3 += __shfl_xor(s3, off);
        }
        if (c == 0) {
            float* out = scores + b * M + hf * 256 + mt * 64 + band * 16 + g * 4;
            out[0] = s0 + b2v;
            out[1] = s1 + b2v;
            out[2] = s2 + b2v;
            out[3] = s3 + b2v;
        }
    }

    // ---- copy suffix: contiguous slice AFTER score (registers dead) -------
    {
        const long base = SPLIT + (long)b * (S2ITER * 512) + t;
#pragma unroll 3
        for (int k = 0; k < S2ITER; ++k) {
            const long i = base + (long)k * 512;
            if (i < COPY_N4) {
                const f32x4 v = __builtin_nontemporal_load(&nf_src[i]);
                __builtin_nontemporal_store(v, &nf_dst[i]);
            }
        }
    }
}

// ---------------------------------------------------------------------------
// Post-kernel (merged): top-16 shortlist -> exact fp32 rescore -> top-k
// select (lax.top_k semantics) -> zero selected rows. 1 block (128T)/row b.
// ---------------------------------------------------------------------------
__global__ __launch_bounds__(128)
void topkrefine_kernel(const float* __restrict__ embed,
                       const float* __restrict__ W1,
                       const float* __restrict__ W2,
                       const float* __restrict__ qh,
                       const int* __restrict__ cand_idx,
                       const float* __restrict__ scores,
                       const int* __restrict__ topk_ptr,
                       float* __restrict__ masked) {
    __shared__ float crows[SHORT][D];
    __shared__ float red[SHORT][D];
    __shared__ int spos[SHORT];
    __shared__ int tnodes[K_MAX];
    __shared__ int kshare;
    const int b = blockIdx.x;
    const int t = threadIdx.x;

    // ---- phase A: approximate top-16 positions (wave 0 only) ----
    if (t < 64) {
        const float* row = scores + b * M;
        float v[8];
        const float4 x0 = ((const float4*)row)[t * 2];
        const float4 x1 = ((const float4*)row)[t * 2 + 1];
        v[0] = x0.x; v[1] = x0.y; v[2] = x0.z; v[3] = x0.w;
        v[4] = x1.x; v[5] = x1.y; v[6] = x1.z; v[7] = x1.w;
        for (int kk = 0; kk < SHORT; ++kk) {
            float bv = v[0];
            int bi = t * 8;
#pragma unroll
            for (int j = 1; j < 8; ++j)
                if (v[j] > bv) { bv = v[j]; bi = t * 8 + j; }
#pragma unroll
            for (int off = 32; off >= 1; off >>= 1) {
                const float ov = __shfl_xor(bv, off);
                const int   oi = __shfl_xor(bi, off);
                if (ov > bv || (ov == bv && oi < bi)) { bv = ov; bi = oi; }
            }
            if (t == 0) spos[kk] = bi;
            if ((bi >> 3) == t) v[bi & 7] = -3.402823466e38f;
        }
    }
    __syncthreads();

    // ---- phase B: exact fp32 rescore of the 16 shortlisted candidates ----
    {
        const int cc = t >> 3;
        const int d0 = (t & 7) * 16;
        const long node = cand_idx[b * M + spos[cc]];
        const float4* rp = (const float4*)(embed + node * D);
        float4* wp = (float4*)&crows[cc][d0];
#pragma unroll
        for (int j = 0; j < 4; ++j) wp[j] = rp[d0 / 4 + j];
    }
    __syncthreads();

    float acc[SHORT];
#pragma unroll
    for (int cc = 0; cc < SHORT; ++cc) acc[cc] = 0.f;
    const float* W1bot = W1 + (long)D * H;
    for (int d = 0; d < D; ++d) {
        const float w1v = W1bot[d * H + t];
#pragma unroll
        for (int cc = 0; cc < SHORT; ++cc)
            acc[cc] = fmaf(crows[cc][d], w1v, acc[cc]);
    }
    const float qv = qh[b * H + t];
    const float w2 = W2[t];
#pragma unroll
    for (int cc = 0; cc < SHORT; ++cc)
        red[cc][t] = fmaxf(qv + acc[cc], 0.f) * w2;
    __syncthreads();

    if (t < 64) {
#pragma unroll
        for (int cc = 0; cc < SHORT; ++cc) {
            float v = red[cc][t] + red[cc][t + 64];
#pragma unroll
            for (int off = 32; off >= 1; off >>= 1) v += __shfl_xor(v, off);
            if (t == 0) red[cc][0] = v;
        }
    }
    __syncthreads();

    // ---- phase C: select top-k (value desc, position asc) ----
    if (t == 0) {
        int k = *topk_ptr;
        if (k > K_MAX) k = K_MAX;
        kshare = k;
        unsigned used = 0;
        for (int kk = 0; kk < k; ++kk) {
            int best = -1, bpos = 0x7fffffff;
            float bv = 0.f;
            for (int cc = 0; cc < SHORT; ++cc) {
                if (used & (1u << cc)) continue;
                const float v = red[cc][0];
                const int p = spos[cc];
                if (best < 0 || v > bv || (v == bv && p < bpos)) {
                    best = cc; bv = v; bpos = p;
                }
            }
            used |= 1u << best;
            tnodes[kk] = cand_idx[b * M + bpos];
        }
    }
    __syncthreads();

    // ---- phase D: zero the selected rows (copy already completed) ----
    for (int kk = 0; kk < kshare; ++kk)
        masked[(long)tnodes[kk] * D + t] = 0.f;
}

// ---------------------------------------------------------------------------
extern "C" void kernel_launch(void* const* d_in, const int* in_sizes, int n_in,
                              void* d_out, int out_size, void* d_ws, size_t ws_size,
                              hipStream_t stream) {
    const float* embed     = (const float*)d_in[0];
    const float* node_feat = (const float*)d_in[1];
    const float* W1        = (const float*)d_in[2];
    const float* b1        = (const float*)d_in[3];
    const float* W2        = (const float*)d_in[4];
    const float* b2        = (const float*)d_in[5];
    const int*   query_idx = (const int*)d_in[6];
    const int*   cand_idx  = (const int*)d_in[7];
    const int*   topk_ptr  = (const int*)d_in[8];

    float* scores = (float*)d_out;                 // B*M
    float* masked = (float*)d_out + (long)BQ * M;  // N*D

    // ws layout
    char* p = (char*)d_ws;
    float*          qh    = (float*)p;              p += (long)BQ * H * 4;
    unsigned short* wTswz = (unsigned short*)p;

    pre_kernel<<<BQ, 128, 0, stream>>>(embed, W1, b1, query_idx, qh, wTswz);

    fused_kernel<<<NCOPYP + NSCORE, 512, 0, stream>>>(
        embed, wTswz, W2, b2, cand_idx, qh, scores,
        (const f32x4*)node_feat, (f32x4*)masked);

    topkrefine_kernel<<<BQ, 128, 0, stream>>>(embed, W1, W2, qh, cand_idx,
                                              scores, topk_ptr, masked);
}